// Round 8
// baseline (371.382 us; speedup 1.0000x reference)
//
#include <hip/hip_runtime.h>
#include <hip/hip_bf16.h>
#include <stdint.h>

typedef __bf16 bf16;
typedef __attribute__((ext_vector_type(8))) __bf16 bf16x8;
typedef __attribute__((ext_vector_type(4))) float f32x4;

#define KREAL 784
#define NTILES 25            // 25 k-tiles of 32
#define TROW   32            // tight rows: B is read per-fragment from L2 now
#define TILE_ELEMS (256 * TROW)   // 8192 elements = 16 KB per k-tile

// ---------------------------------------------------------------------------
// Prep: fold 3x3 VALID cross-correlation into w1, emit k-tiled:
//   W[tile][n][kk], kk in [0,32), zero for k >= 784 (tile 24, kk >= 16).
//   Tight 64 B rows: each MFMA B-fragment is a fully-coalesced 1 KB wave read.
// ---------------------------------------------------------------------------
__global__ __launch_bounds__(256) void prep_w1tt(const float* __restrict__ w_conv,
                                                 const float* __restrict__ w1,
                                                 bf16* __restrict__ W) {
    const int tile = blockIdx.x >> 5;
    const int kk   = blockIdx.x & 31;
    const int n    = threadIdx.x;
    const int k    = tile * 32 + kk;
    float s = 0.0f;
    if (k < KREAL) {
        const int r = k / 28, c = k % 28;
        #pragma unroll
        for (int di = 0; di < 3; ++di) {
            const int i = r - di;
            if (i < 0 || i >= 26) continue;
            #pragma unroll
            for (int dj = 0; dj < 3; ++dj) {
                const int j = c - dj;
                if (j < 0 || j >= 26) continue;
                s += w_conv[di * 3 + dj] * w1[(i * 26 + j) * 256 + n];
            }
        }
    }
    W[(size_t)tile * TILE_ELEMS + n * TROW + kk] = (bf16)s;
}

// DPP cross-lane add (VALU pipe, no DS ops). 0xB1=xor1, 0x4E=xor2,
// 0x124=row_ror:4, 0x128=row_ror:8 (ring-sum of uniform quad-sums).
template <int CTRL>
__device__ __forceinline__ float dpp_add(float s) {
    int v = __builtin_amdgcn_update_dpp(0, __float_as_int(s), CTRL, 0xf, 0xf, false);
    return s + __int_as_float(v);
}

__device__ __forceinline__ bf16x8 cvt8(float4 lo, float4 hi, float m) {
    bf16x8 r;
    r[0] = (bf16)(lo.x * m); r[1] = (bf16)(lo.y * m);
    r[2] = (bf16)(lo.z * m); r[3] = (bf16)(lo.w * m);
    r[4] = (bf16)(hi.x * m); r[5] = (bf16)(hi.y * m);
    r[6] = (bf16)(hi.z * m); r[7] = (bf16)(hi.w * m);
    return r;
}

// ---------------------------------------------------------------------------
// Fused: out = relu(x @ W1' + b1) @ w2 + b2
// BARRIER-FREE main loop, register-pipelined B (the fix for R1's collapse):
//   M=64/block (grid 1024), 4 waves, each wave = 64 rows x 64 cols
//   (acc[4][4]); per iter per wave: 4 B-frag loads (dwordx4, coalesced 1 KB,
//   L2-hot 400 KB W) prefetched ONE TILE AHEAD into named registers, and
//   8 A float4 loads prefetched one tile ahead. No LDS, no s_barrier, no
//   vmcnt drains in the loop -> waves free-run and self-stagger their HBM
//   requests (the R2/R6/R7-null + all-pipes-idle signature pointed at
//   barrier lockstep as the residual cost). Compiler's per-register waitcnt
//   gives: MFMA waits only on B loaded last iter (free), cvt waits only on
//   this iter's A (mostly covered).
// Epilogue: DPP 16-lane reduction (R5 win, zero DS ops) + 16 KB LDS 4-way
// cross-wave combine (idempotent; first barrier of the kernel).
// ---------------------------------------------------------------------------
__global__ __launch_bounds__(256, 2) void fused_mlp(
    const float* __restrict__ x,    // (65536, 784)
    const bf16*  __restrict__ W,    // k-tiled W1' (25*8192 bf16)
    const float* __restrict__ b1,   // (256)
    const float* __restrict__ w2,   // (256, 10)
    const float* __restrict__ b2,   // (10)
    float* __restrict__ out)        // (65536, 10)
{
    __shared__ float part[4096];    // 16 KB: [nh][mt][r][q][16]

    const int t    = threadIdx.x;
    const int wave = t >> 6;        // nh: this wave's 64-col group
    const int lane = t & 63;
    const int c    = lane & 15;     // MFMA col / A-row within 16-tile
    const int q    = lane >> 4;     // MFMA quad (k-chunk selector)

    const int row0 = blockIdx.x * 64;

    // A: lane (c,q), m-tile mt -> row row0 + mt*16 + c, k-chunk q*8..q*8+7
    //    (all 4 waves read the same rows; L1/L2 serve the duplicates)
    const float* ar = x + (size_t)(row0 + c) * KREAL + q * 8;
    // B: frag nt of tile T at bp + T*TILE_ELEMS + nt*512
    const bf16* bp = W + (wave * 64 + c) * TROW + q * 8;

    f32x4 acc[4][4];
    #pragma unroll
    for (int mt = 0; mt < 4; ++mt)
        #pragma unroll
        for (int nt = 0; nt < 4; ++nt)
            acc[mt][nt] = (f32x4){0.f, 0.f, 0.f, 0.f};

    float4 fa[4], fb[4];
    bf16x8 a[4], BX[4], BY[4];

    // ---- prologue: A(0) + B(0) loads, cvt A(0) ----
    #pragma unroll
    for (int mt = 0; mt < 4; ++mt) {
        const float* p = ar + (size_t)(mt * 16) * KREAL;
        fa[mt] = *(const float4*)p;
        fb[mt] = *(const float4*)(p + 4);
    }
    #pragma unroll
    for (int nt = 0; nt < 4; ++nt)
        BX[nt] = *(const bf16x8*)(bp + nt * 512);
    #pragma unroll
    for (int mt = 0; mt < 4; ++mt) a[mt] = cvt8(fa[mt], fb[mt], 1.f);

    // KSTEP: MFMA on BC; prefetch A(IT+1)+B(IT+1) (B into BN); cvt A(IT+1).
#define KSTEP(IT, BC, BN)                                                      \
    do {                                                                       \
        const bool more_ = (IT) + 1 < NTILES;                                  \
        float okm_ = 1.f;                                                      \
        if (more_) {                                                           \
            const int kn_   = ((IT) + 1) * 32;                                 \
            const bool ok_  = (kn_ + q * 8) < KREAL;  /* tile 24, q>=2 only */ \
            okm_ = ok_ ? 1.f : 0.f;                                            \
            const int koff_ = ok_ ? kn_ : 0;                                   \
            _Pragma("unroll")                                                  \
            for (int mt = 0; mt < 4; ++mt) {        /* A first (oldest) */     \
                const float* p_ = ar + (size_t)(mt * 16) * KREAL + koff_;      \
                fa[mt] = *(const float4*)p_;                                   \
                fb[mt] = *(const float4*)(p_ + 4);                             \
            }                                                                  \
            const bf16* bt_ = bp + (size_t)((IT) + 1) * TILE_ELEMS;            \
            _Pragma("unroll")                                                  \
            for (int nt = 0; nt < 4; ++nt)          /* B next (youngest) */    \
                BN[nt] = *(const bf16x8*)(bt_ + nt * 512);                     \
        }                                                                      \
        _Pragma("unroll")                                                      \
        for (int nt = 0; nt < 4; ++nt)              /* 16 MFMAs on BC */       \
            _Pragma("unroll")                                                  \
            for (int mt = 0; mt < 4; ++mt)                                     \
                acc[mt][nt] = __builtin_amdgcn_mfma_f32_16x16x32_bf16(         \
                    a[mt], BC[nt], acc[mt][nt], 0, 0, 0);                      \
        if (more_) {                                /* cvt A(IT+1) */          \
            _Pragma("unroll")                                                  \
            for (int mt = 0; mt < 4; ++mt) a[mt] = cvt8(fa[mt], fb[mt], okm_); \
        }                                                                      \
    } while (0)

    #pragma unroll 1
    for (int base = 0; base < NTILES - 1; base += 2) {
        KSTEP(base,     BX, BY);
        KSTEP(base + 1, BY, BX);
    }
    KSTEP(NTILES - 1, BX, BY);   // it=24: MFMA only (NTILES odd -> cur=BX)
#undef KSTEP

    // ---- epilogue: h = relu(acc + b1); partial (64-col) h @ w2 ----
    // C/D layout: col = lane&15 (= n within tile), row = q*4 + reg
    float bl[4];
    #pragma unroll
    for (int nt = 0; nt < 4; ++nt) bl[nt] = b1[wave * 64 + nt * 16 + c];

    #pragma unroll
    for (int mt = 0; mt < 4; ++mt)
        #pragma unroll
        for (int nt = 0; nt < 4; ++nt)
            #pragma unroll
            for (int r = 0; r < 4; ++r) {
                float v = acc[mt][nt][r] + bl[nt];
                acc[mt][nt][r] = v > 0.f ? v : 0.f;
            }

    float keep[4][4];
    #pragma unroll
    for (int mt = 0; mt < 4; ++mt)
        #pragma unroll
        for (int r = 0; r < 4; ++r) keep[mt][r] = 0.f;

    #pragma unroll 1
    for (int j = 0; j < 10; ++j) {
        float wj[4];
        #pragma unroll
        for (int nt = 0; nt < 4; ++nt) wj[nt] = w2[(wave * 64 + nt * 16 + c) * 10 + j];
        #pragma unroll
        for (int mt = 0; mt < 4; ++mt)
            #pragma unroll
            for (int r = 0; r < 4; ++r) {
                float s = 0.f;
                #pragma unroll
                for (int nt = 0; nt < 4; ++nt) s += acc[mt][nt][r] * wj[nt];
                s = dpp_add<0xB1>(s);    // lane ^ 1
                s = dpp_add<0x4E>(s);    // lane ^ 2
                s = dpp_add<0x124>(s);   // row_ror:4 (quad-sums uniform)
                s = dpp_add<0x128>(s);   // row_ror:8
                if (c == j) keep[mt][r] = s;
            }
    }

    // 4-way cross-wave combine via LDS (the kernel's only barrier).
    #pragma unroll
    for (int mt = 0; mt < 4; ++mt)
        #pragma unroll
        for (int r = 0; r < 4; ++r)
            if (c < 10)
                part[((((wave * 4 + mt) * 4 + r) * 4 + q) << 4) + c] = keep[mt][r];
    __syncthreads();
    for (int idx = t; idx < 640; idx += 256) {
        const int row = idx / 10, cc = idx - row * 10;
        const int mt = row >> 4, qq = (row >> 2) & 3, rr = row & 3;
        float s = b2[cc];
        #pragma unroll
        for (int nh = 0; nh < 4; ++nh)
            s += part[((((nh * 4 + mt) * 4 + rr) * 4 + qq) << 4) + cc];
        out[(size_t)(row0 + row) * 10 + cc] = s;
    }
}

extern "C" void kernel_launch(void* const* d_in, const int* in_sizes, int n_in,
                              void* d_out, int out_size, void* d_ws, size_t ws_size,
                              hipStream_t stream) {
    const float* x  = (const float*)d_in[0];
    const float* wc = (const float*)d_in[1];
    const float* w1 = (const float*)d_in[2];
    const float* b1 = (const float*)d_in[3];
    const float* w2 = (const float*)d_in[4];
    const float* b2 = (const float*)d_in[5];
    float* out = (float*)d_out;
    bf16* W = (bf16*)d_ws;  // 25 * 8192 * 2 B = 400 KB scratch

    prep_w1tt<<<dim3(NTILES * 32), dim3(256), 0, stream>>>(wc, w1, W);
    fused_mlp<<<dim3(65536 / 64), dim3(256), 0, stream>>>(x, W, b1, w2, b2, out);
}